// Round 1
// 249.178 us; speedup vs baseline: 1.0386x; 1.0386x over previous
//
#include <hip/hip_runtime.h>
#include <hip/hip_bf16.h>
#include <stdint.h>

// Causal MHA, B=8 S=2048 E=768 N=12 H=64. fp32 in/out, bf16 MFMA compute.
// prep -> QKV gemm (256x256 8-phase, counted vmcnt, setprio)
// -> flash attention (LDS-staged K/V, register-P, paired strips)
// -> out gemm (same 256x256 8-phase structure).

#define B_ 8
#define S_ 2048
#define E_ 768
#define NHEADS 12
#define HD 64
#define BS (B_*S_)        // 16384
#define NHD (NHEADS*HD)   // 768

typedef short bf16x8 __attribute__((ext_vector_type(8)));   // 8 bf16 = 4 VGPR
typedef short bf16x4 __attribute__((ext_vector_type(4)));
typedef float f32x4  __attribute__((ext_vector_type(4)));   // MFMA C/D frag
typedef __hip_bfloat16 bf16;

typedef const __attribute__((address_space(1))) char* as1_t;
typedef __attribute__((address_space(3))) char* as3_t;

__device__ __forceinline__ f32x4 mfma16(bf16x8 a, bf16x8 b, f32x4 c) {
    return __builtin_amdgcn_mfma_f32_16x16x32_bf16(a, b, c, 0, 0, 0);
}
__device__ __forceinline__ bf16x8 ld8(const bf16* p) {
    return *reinterpret_cast<const bf16x8*>(p);
}
// async global->LDS, 16B/lane; lds dest = wave-uniform base + lane*16
__device__ __forceinline__ void gload16(const bf16* g, bf16* l) {
    __builtin_amdgcn_global_load_lds((as1_t)g, (as3_t)l, 16, 0, 0);
}
__device__ __forceinline__ bf16x8 pack8(f32x4 a, f32x4 b) {
    union { bf16x8 v; __hip_bfloat162 h[4]; } u;
    u.h[0] = __float22bfloat162_rn(make_float2(a[0], a[1]));
    u.h[1] = __float22bfloat162_rn(make_float2(a[2], a[3]));
    u.h[2] = __float22bfloat162_rn(make_float2(b[0], b[1]));
    u.h[3] = __float22bfloat162_rn(make_float2(b[2], b[3]));
    return u.v;
}

// ---------------- prep: fp32 -> bf16 casts + weight transposes ----------------
__global__ __launch_bounds__(256) void prep_kernel(
    const float* __restrict__ x,  const float* __restrict__ Wq,
    const float* __restrict__ Wk, const float* __restrict__ Wv,
    const float* __restrict__ Wo,
    bf16* __restrict__ xb,  bf16* __restrict__ WqT, bf16* __restrict__ WkT,
    bf16* __restrict__ WvT, bf16* __restrict__ WoT)
{
    const int tid = blockIdx.x * 256 + threadIdx.x;
    const int nth = gridDim.x * 256;
    for (int i = tid; i < BS*E_; i += nth)
        xb[i] = __float2bfloat16(x[i]);
    for (int i = tid; i < NHD*E_; i += nth) {
        const int c = i / E_;
        const int e = i - c*E_;
        const int n = c >> 6, h = c & 63;
        const int src = (n*E_ + e)*HD + h;       // W_[n][e][h]
        WqT[i] = __float2bfloat16(Wq[src]);
        WkT[i] = __float2bfloat16(Wk[src]);
        WvT[i] = __float2bfloat16(Wv[src]);
        WoT[e*NHD + c] = __float2bfloat16(Wo[i]); // Wo flat[c*E+e] = W_O[n][h][e]
    }
}

// ======================= 256x256 8-phase GEMM core ===========================
// BM=BN=256, BK=64, 8 waves (wm 0..1, wn 0..3), wave tile 128x64.
// LDS per matrix tile: 4 subtiles (rhalf 0..1, khalf 0..1) of 128 rows x 32 cols,
// each stored fragment-major: chunk p = rg*64 + lane (rg=row>>4), so a frag read
// is 64 consecutive 16B chunks (conflict-free), and global_load_lds writes the
// same linear order. Double-buffered: 2 x (32KB A + 32KB B) = 128 KB LDS.
//
// Per 8-phase iteration: 2 K-tiles. Phase = {4-8 ds_read_b128, 2 gload_lds,
// barrier, lgkmcnt(0), setprio(1), 16 MFMA (one 32-row C-quadrant x K=64),
// setprio(0), [vmcnt(4) at phases 4/8], barrier}. B-frags are loaded only in a
// K-tile's q0 phase and held in registers for q1..q3, which frees the B region
// for overwrite from phase q1 onward. Stage ledger (iteration i):
//   ph1-2: KT(2i+1) A -> buf1   (buf1.A last read prev ph8; barrier between)
//   ph3-4: KT(2i+2) B -> buf0   (buf0.B read only in ph1)
//   ph5-6: KT(2i+2) A -> buf0   (buf0.A last read ph4)
//   ph7-8: KT(2i+3) B -> buf1   (buf1.B read only in ph5)
// vmcnt(4) at ph4 -> prev ph7/8 + ph1/2 landed (everything buf1 needs for ph5-8);
// vmcnt(4) at ph8 -> ph3..ph6 landed (everything buf0 needs for next ph1-4).
// Loads are never drained to 0 in the main loop (T4).

#define FENCE() asm volatile("" ::: "memory")
#define VMCNT4() asm volatile("s_waitcnt vmcnt(4)" ::: "memory")

// stage half-tile (rows rh*128..+128, both khalves) of K-tile kt into LDS tile dst
#define STG(dst, gbase, kt, rh) do {                                              \
    const bf16* _s = (gbase) + (size_t)((rh)*128 + w*16 + l16)*768 + (kt)*64 + kc8;\
    gload16(_s,      &(dst)[((rh)*2 + 0)*4096 + w*512]);                          \
    gload16(_s + 32, &(dst)[((rh)*2 + 1)*4096 + w*512]);                          \
} while (0)

#define PHASE(bufA, bufB, q, LOADB, STAGE, WAIT) do {                             \
    if (LOADB) {                                                                  \
        _Pragma("unroll") for (int n = 0; n < 4; ++n)                             \
        _Pragma("unroll") for (int ks = 0; ks < 2; ++ks)                          \
            bfr[n][ks] = ld8(&(bufB)[((wn>>1)*2 + ks)*4096 +                      \
                                     ((wn&1)*4 + n)*512 + lane*8]);               \
    }                                                                             \
    bf16x8 afr[2][2];                                                             \
    _Pragma("unroll") for (int m = 0; m < 2; ++m)                                 \
    _Pragma("unroll") for (int ks = 0; ks < 2; ++ks)                              \
        afr[m][ks] = ld8(&(bufA)[(wm*2 + ks)*4096 + ((q)*2 + m)*512 + lane*8]);   \
    STAGE;                                                                        \
    FENCE(); __builtin_amdgcn_s_barrier(); FENCE();                               \
    asm volatile("s_waitcnt lgkmcnt(0)" ::: "memory");                            \
    __builtin_amdgcn_s_setprio(1);                                                \
    _Pragma("unroll") for (int m = 0; m < 2; ++m)                                 \
    _Pragma("unroll") for (int n = 0; n < 4; ++n)                                 \
    _Pragma("unroll") for (int ks = 0; ks < 2; ++ks)                              \
        acc[(q)*2 + m][n] = mfma16(afr[m][ks], bfr[n][ks], acc[(q)*2 + m][n]);    \
    __builtin_amdgcn_s_setprio(0);                                                \
    WAIT;                                                                         \
    FENCE(); __builtin_amdgcn_s_barrier(); FENCE();                               \
} while (0)

// K = 768 for both GEMMs: 12 K-tiles of 64 -> 6 iterations of 2 K-tiles.
#define GEMM256_BODY(Ab, Bb)                                                      \
    f32x4 acc[8][4];                                                              \
    _Pragma("unroll") for (int mf = 0; mf < 8; ++mf)                              \
    _Pragma("unroll") for (int nf = 0; nf < 4; ++nf)                              \
        acc[mf][nf] = (f32x4){0.f, 0.f, 0.f, 0.f};                                \
    bf16x8 bfr[4][2];                                                             \
    STG(sA[0], Ab, 0, 0); STG(sA[0], Ab, 0, 1);                                   \
    STG(sB[0], Bb, 0, 0); STG(sB[0], Bb, 0, 1);                                   \
    STG(sB[1], Bb, 1, 0); STG(sB[1], Bb, 1, 1);                                   \
    VMCNT4();                                                                     \
    FENCE(); __builtin_amdgcn_s_barrier(); FENCE();                               \
    _Pragma("unroll 1")                                                           \
    for (int i = 0; i < 6; ++i) {                                                 \
        const int kA  = 2*i + 1;                                                  \
        const int kN  = (2*i + 2 < 12) ? 2*i + 2 : 11;                            \
        const int kN3 = (2*i + 3 < 12) ? 2*i + 3 : 11;                            \
        PHASE(sA[0], sB[0], 0, 1, STG(sA[1], Ab, kA,  0), (void)0);               \
        PHASE(sA[0], sB[0], 1, 0, STG(sA[1], Ab, kA,  1), (void)0);               \
        PHASE(sA[0], sB[0], 2, 0, STG(sB[0], Bb, kN,  0), (void)0);               \
        PHASE(sA[0], sB[0], 3, 0, STG(sB[0], Bb, kN,  1), VMCNT4());              \
        PHASE(sA[1], sB[1], 0, 1, STG(sA[0], Ab, kN,  0), (void)0);               \
        PHASE(sA[1], sB[1], 1, 0, STG(sA[0], Ab, kN,  1), (void)0);               \
        PHASE(sA[1], sB[1], 2, 0, STG(sB[1], Bb, kN3, 0), (void)0);               \
        PHASE(sA[1], sB[1], 3, 0, STG(sB[1], Bb, kN3, 1), VMCNT4());              \
    }

// ---------------- QKV projection GEMM (256x256 8-phase) ----------------
// WT = concatenated [WqT; WkT; WvT] = [2304][768]; tn 0..8 spans it.
__global__ __launch_bounds__(512, 2) void qkv_gemm256(
    const bf16* __restrict__ xb, const bf16* __restrict__ WT,
    const float* __restrict__ bq, const float* __restrict__ bk, const float* __restrict__ bv,
    bf16* __restrict__ Qb, bf16* __restrict__ Kb, bf16* __restrict__ VTb)
{
    __shared__ __align__(16) bf16 sA[2][16384];
    __shared__ __align__(16) bf16 sB[2][16384];

    const int tm = blockIdx.x, tn = blockIdx.y;
    const int lane = threadIdx.x & 63;
    const int w    = threadIdx.x >> 6;      // 0..7
    const int wm = w >> 2, wn = w & 3;
    const int l16 = lane & 15, quad = lane >> 4;
    const int kc8 = quad * 8;
    const bf16* Ab = xb + (size_t)tm*256*E_;
    const bf16* Bb = WT + (size_t)tn*256*E_;

    GEMM256_BODY(Ab, Bb);

    const int mat = tn / 3;                 // 0=Q 1=K 2=V
    const int cloc0 = (tn - mat*3)*256 + wn*64;
    const float* bias = (mat==0) ? bq : (mat==1) ? bk : bv;
    const float scale = (mat==0) ? 0.125f * 1.44269504088896340736f : 1.0f;
    bf16* dstQK = (mat==0) ? Qb : Kb;
    #pragma unroll
    for (int nf = 0; nf < 4; ++nf) {
        const int col = cloc0 + nf*16 + l16;       // 0..767 within matrix
        const int hn = col >> 6, h = col & 63;
        const float bb = bias[col];
        #pragma unroll
        for (int mf = 0; mf < 8; ++mf) {
            const int row = tm*256 + wm*128 + mf*16 + quad*4;
            const int bi = row >> 11;              // / S_
            const int s  = row & (S_-1);
            if (mat < 2) {                         // Q,K -> [B][N][S][H]
                bf16* d = dstQK + ((size_t)(bi*NHEADS + hn)*S_ + s)*HD + h;
                #pragma unroll
                for (int r = 0; r < 4; ++r)
                    d[(size_t)r*HD] = __float2bfloat16((acc[mf][nf][r] + bb)*scale);
            } else {                               // V -> transposed [B][N][H][S]
                bf16* d = VTb + ((size_t)(bi*NHEADS + hn)*HD + h)*S_ + s;
                union { bf16x4 v; bf16 e[4]; } u;
                #pragma unroll
                for (int r = 0; r < 4; ++r) u.e[r] = __float2bfloat16(acc[mf][nf][r] + bb);
                *reinterpret_cast<bf16x4*>(d) = u.v;   // s%4==0 -> 8B aligned
            }
        }
    }
}

// ---------------- output projection (256x256 8-phase): out = Z @ Wo + bo -----
__global__ __launch_bounds__(512, 2) void out_gemm256(
    const bf16* __restrict__ Z, const bf16* __restrict__ WoT,
    const float* __restrict__ bo, float* __restrict__ out)
{
    __shared__ __align__(16) bf16 sA[2][16384];
    __shared__ __align__(16) bf16 sB[2][16384];

    const int tm = blockIdx.x, tn = blockIdx.y;
    const int lane = threadIdx.x & 63;
    const int w    = threadIdx.x >> 6;
    const int wm = w >> 2, wn = w & 3;
    const int l16 = lane & 15, quad = lane >> 4;
    const int kc8 = quad * 8;
    const bf16* Ab = Z   + (size_t)tm*256*NHD;
    const bf16* Bb = WoT + (size_t)tn*256*NHD;

    GEMM256_BODY(Ab, Bb);

    #pragma unroll
    for (int nf = 0; nf < 4; ++nf) {
        const int col = tn*256 + wn*64 + nf*16 + l16;
        const float bb = bo[col];
        #pragma unroll
        for (int mf = 0; mf < 8; ++mf) {
            const int row = tm*256 + wm*128 + mf*16 + quad*4;
            float* d = out + (size_t)row*E_ + col;
            #pragma unroll
            for (int r = 0; r < 4; ++r)
                d[(size_t)r*E_] = acc[mf][nf][r] + bb;
        }
    }
}

// ---------------- flash attention (LDS-staged K/V, double-buffered) -----------
__global__ __launch_bounds__(256, 3) void attn_kernel(
    const bf16* __restrict__ Qb, const bf16* __restrict__ Kb,
    const bf16* __restrict__ VTb, bf16* __restrict__ Z)
{
    __shared__ __align__(16) bf16 sK[2][64*64];
    __shared__ __align__(16) bf16 sV[2][64*64];

    const int id = blockIdx.x;
    const int bx = id / 96;                  // 0..7
    const int g  = id - bx*96;
    const int hn = g % NHEADS, b = g / NHEADS;
    const int tid  = threadIdx.x;
    const int w    = tid >> 6;
    const int lane = tid & 63;
    const int l16 = lane & 15, quad = lane >> 4;
    const size_t bn = (size_t)b*NHEADS + hn;

    const bf16* Qbase = Qb  + bn*S_*HD;
    const bf16* Kbase = Kb  + bn*S_*HD;
    const bf16* Vbase = VTb + bn*HD*S_;

    const int mA = tid, mB = tid + 256;
    const int rA = mA >> 3, cgA = mA & 7;
    const int rB = mB >> 3, cgB = mB & 7;
    const int slA = (rA*8 + ((cgA + rA + (rA>>3)) & 7)) * 8;
    const int slB = (rB*8 + ((cgB + rB + (rB>>3)) & 7)) * 8;
    const size_t vofA = (size_t)rA*S_ + cgA*8;
    const size_t vofB = (size_t)rB*S_ + cgB*8;

    const int kperm = (l16 >> 2)*8 + (l16 & 3);
    int kidx[2][2][2];
    #pragma unroll
    for (int c=0;c<2;c++)
        #pragma unroll
        for (int bg=0;bg<2;bg++)
            #pragma unroll
            for (int hf=0;hf<2;hf++) {
                const int r = 32*c + 4*bg + kperm;
                const int q = hf*4 + quad;
                kidx[c][bg][hf] = (r*8 + ((q + r + (r>>3)) & 7)) * 8;
            }
    int vidx[4][2];
    #pragma unroll
    for (int ht=0;ht<4;ht++)
        #pragma unroll
        for (int c=0;c<2;c++) {
            const int rho = ht*16 + l16;
            const int q = c*4 + quad;
            vidx[ht][c] = (rho*8 + ((q + rho + (rho>>3)) & 7)) * 8;
        }

    #pragma unroll
    for (int half = 0; half < 2; ++half) {
        const int qblk = half ? (S_/128 - 1 - bx) : bx;
        const int ktb  = 2*qblk + 1;
        const int ktw  = 2*qblk + (w >> 1);
        const int qbase = qblk*128 + w*32;

        bf16x8 bqf[2][2];
        #pragma unroll
        for (int qi=0;qi<2;qi++)
            #pragma unroll
            for (int hf=0;hf<2;hf++)
                bqf[qi][hf] = ld8(Qbase + (size_t)(qbase + qi*16 + l16)*HD + hf*32 + quad*8);

        f32x4 acc[2][4];
        #pragma unroll
        for (int qi=0;qi<2;qi++)
            #pragma unroll
            for (int ht=0;ht<4;ht++) acc[qi][ht] = (f32x4){0.f,0.f,0.f,0.f};
        float lsum[2] = {0.f, 0.f};

        bf16x8 k0 = ld8(Kbase + (size_t)mA*8);
        bf16x8 k1 = ld8(Kbase + (size_t)mB*8);
        bf16x8 v0 = ld8(Vbase + vofA);
        bf16x8 v1 = ld8(Vbase + vofB);
        *reinterpret_cast<bf16x8*>(&sK[0][slA]) = k0;
        *reinterpret_cast<bf16x8*>(&sK[0][slB]) = k1;
        *reinterpret_cast<bf16x8*>(&sV[0][slA]) = v0;
        *reinterpret_cast<bf16x8*>(&sV[0][slB]) = v1;
        __syncthreads();

        for (int kt = 0; kt <= ktb; ++kt) {
            if (kt < ktb) {
                const size_t kt1 = (size_t)(kt+1)*64;
                k0 = ld8(Kbase + kt1*HD + (size_t)mA*8);
                k1 = ld8(Kbase + kt1*HD + (size_t)mB*8);
                v0 = ld8(Vbase + vofA + kt1);
                v1 = ld8(Vbase + vofB + kt1);
            }
            if (kt <= ktw) {
                const bf16* kb = sK[kt & 1];
                const bf16* vb = sV[kt & 1];
                #pragma unroll
                for (int c=0;c<2;c++) {
                    const bf16x8 akA0 = ld8(kb + kidx[c][0][0]);
                    const bf16x8 akA1 = ld8(kb + kidx[c][0][1]);
                    const bf16x8 akB0 = ld8(kb + kidx[c][1][0]);
                    const bf16x8 akB1 = ld8(kb + kidx[c][1][1]);
                    bf16x8 av[4];
                    #pragma unroll
                    for (int ht=0;ht<4;ht++) av[ht] = ld8(vb + vidx[ht][c]);

                    #pragma unroll
                    for (int qi=0;qi<2;qi++) {
                        f32x4 s0 = (f32x4){0.f,0.f,0.f,0.f};
                        s0 = mfma16(akA0, bqf[qi][0], s0);
                        s0 = mfma16(akA1, bqf[qi][1], s0);
                        f32x4 s1 = (f32x4){0.f,0.f,0.f,0.f};
                        s1 = mfma16(akB0, bqf[qi][0], s1);
                        s1 = mfma16(akB1, bqf[qi][1], s1);
                        if (kt == ktw) {
                            const int q  = qbase + qi*16 + l16;
                            const int kb0 = kt*64 + c*32 + quad*8;
                            #pragma unroll
                            for (int r=0;r<4;r++) {
                                s0[r] = (kb0 + r     > q) ? -1e30f : s0[r];
                                s1[r] = (kb0 + 4 + r > q) ? -1e30f : s1[r];
                            }
                        }
                        float ls = 0.f;
                        #pragma unroll
                        for (int r=0;r<4;r++) {
                            s0[r] = __builtin_amdgcn_exp2f(s0[r]);
                            s1[r] = __builtin_amdgcn_exp2f(s1[r]);
                            ls += s0[r] + s1[r];
                        }
                        lsum[qi] += ls;
                        const bf16x8 pf = pack8(s0, s1);
                        #pragma unroll
                        for (int ht=0;ht<4;ht++)
                            acc[qi][ht] = mfma16(av[ht], pf, acc[qi][ht]);
                    }
                }
            }
            if (kt < ktb) {
                const int nb = (kt+1) & 1;
                *reinterpret_cast<bf16x8*>(&sK[nb][slA]) = k0;
                *reinterpret_cast<bf16x8*>(&sK[nb][slB]) = k1;
                *reinterpret_cast<bf16x8*>(&sV[nb][slA]) = v0;
                *reinterpret_cast<bf16x8*>(&sV[nb][slB]) = v1;
            }
            __syncthreads();
        }

        #pragma unroll
        for (int qi=0;qi<2;qi++) {
            float rs = lsum[qi];
            rs += __shfl_xor(rs, 16, 64);
            rs += __shfl_xor(rs, 32, 64);
            const float inv_l = 1.0f / rs;
            const int q = qbase + qi*16 + l16;
            bf16* zp = Z + ((size_t)b*S_ + q)*NHD + (size_t)hn*HD + quad*4;
            #pragma unroll
            for (int ht=0;ht<4;ht++) {
                union { bf16x4 v; bf16 e[4]; } u;
                #pragma unroll
                for (int r=0;r<4;r++) u.e[r] = __float2bfloat16(acc[qi][ht][r] * inv_l);
                *reinterpret_cast<bf16x4*>(zp + ht*16) = u.v;
            }
        }
    }
}

extern "C" void kernel_launch(void* const* d_in, const int* in_sizes, int n_in,
                              void* d_out, int out_size, void* d_ws, size_t ws_size,
                              hipStream_t stream)
{
    const float* x  = (const float*)d_in[0];
    const float* Wq = (const float*)d_in[1];
    const float* Wk = (const float*)d_in[2];
    const float* Wv = (const float*)d_in[3];
    const float* Wo = (const float*)d_in[4];
    const float* bq = (const float*)d_in[5];
    const float* bk = (const float*)d_in[6];
    const float* bv = (const float*)d_in[7];
    const float* bo = (const float*)d_in[8];
    float* out = (float*)d_out;

    char* ws = (char*)d_ws;
    size_t off = 0;
    auto alloc = [&](size_t bytes){ char* p = ws + off; off += (bytes + 255) & ~(size_t)255; return p; };
    bf16* xb  = (bf16*)alloc((size_t)BS*E_*2);
    bf16* WT  = (bf16*)alloc((size_t)3*NHD*E_*2);  // [WqT; WkT; WvT] = [2304][768]
    bf16* WoT = (bf16*)alloc((size_t)E_*NHD*2);
    bf16* Qb  = (bf16*)alloc((size_t)BS*NHD*2);   // [B][N][S][H], pre-scaled log2e/8
    bf16* Kb  = (bf16*)alloc((size_t)BS*NHD*2);   // [B][N][S][H]
    bf16* VTb = (bf16*)alloc((size_t)BS*NHD*2);   // [B][N][H][S]
    bf16* Zb  = (bf16*)alloc((size_t)BS*NHD*2);   // [BS][NHD]

    bf16* WqT = WT;
    bf16* WkT = WT + (size_t)NHD*E_;
    bf16* WvT = WT + (size_t)2*NHD*E_;

    prep_kernel<<<4096, 256, 0, stream>>>(x, Wq, Wk, Wv, Wo, xb, WqT, WkT, WvT, WoT);
    qkv_gemm256<<<dim3(BS/256, 9), 512, 0, stream>>>(xb, WT, bq, bk, bv, Qb, Kb, VTb);
    attn_kernel<<<768, 256, 0, stream>>>(Qb, Kb, VTb, Zb);
    out_gemm256<<<dim3(BS/256, E_/256), 512, 0, stream>>>(Zb, WoT, bo, out);
}

// Round 2
// 238.236 us; speedup vs baseline: 1.0863x; 1.0459x over previous
//
#include <hip/hip_runtime.h>
#include <hip/hip_bf16.h>
#include <stdint.h>

// Causal MHA, B=8 S=2048 E=768 N=12 H=64. fp32 in/out, bf16 MFMA compute.
// prep -> QKV gemm (256x192 8-phase, counted vmcnt, distinct LDS buffers)
// -> flash attention (LDS-staged K/V, register-P, paired strips)
// -> out gemm (same 256x192 8-phase structure).

#define B_ 8
#define S_ 2048
#define E_ 768
#define NHEADS 12
#define HD 64
#define BS (B_*S_)        // 16384
#define NHD (NHEADS*HD)   // 768

typedef short bf16x8 __attribute__((ext_vector_type(8)));   // 8 bf16 = 4 VGPR
typedef short bf16x4 __attribute__((ext_vector_type(4)));
typedef float f32x4  __attribute__((ext_vector_type(4)));   // MFMA C/D frag
typedef __hip_bfloat16 bf16;

typedef const __attribute__((address_space(1))) char* as1_t;
typedef __attribute__((address_space(3))) char* as3_t;

__device__ __forceinline__ f32x4 mfma16(bf16x8 a, bf16x8 b, f32x4 c) {
    return __builtin_amdgcn_mfma_f32_16x16x32_bf16(a, b, c, 0, 0, 0);
}
__device__ __forceinline__ bf16x8 ld8(const bf16* p) {
    return *reinterpret_cast<const bf16x8*>(p);
}
// async global->LDS, 16B/lane; lds dest = wave-uniform base + lane*16
__device__ __forceinline__ void gload16(const bf16* g, bf16* l) {
    __builtin_amdgcn_global_load_lds((as1_t)g, (as3_t)l, 16, 0, 0);
}
__device__ __forceinline__ bf16x8 pack8(f32x4 a, f32x4 b) {
    union { bf16x8 v; __hip_bfloat162 h[4]; } u;
    u.h[0] = __float22bfloat162_rn(make_float2(a[0], a[1]));
    u.h[1] = __float22bfloat162_rn(make_float2(a[2], a[3]));
    u.h[2] = __float22bfloat162_rn(make_float2(b[0], b[1]));
    u.h[3] = __float22bfloat162_rn(make_float2(b[2], b[3]));
    return u.v;
}

// ---------------- prep: fp32 -> bf16 casts + weight transposes ----------------
__global__ __launch_bounds__(256) void prep_kernel(
    const float* __restrict__ x,  const float* __restrict__ Wq,
    const float* __restrict__ Wk, const float* __restrict__ Wv,
    const float* __restrict__ Wo,
    bf16* __restrict__ xb,  bf16* __restrict__ WqT, bf16* __restrict__ WkT,
    bf16* __restrict__ WvT, bf16* __restrict__ WoT)
{
    const int tid = blockIdx.x * 256 + threadIdx.x;
    const int nth = gridDim.x * 256;
    for (int i = tid; i < BS*E_; i += nth)
        xb[i] = __float2bfloat16(x[i]);
    for (int i = tid; i < NHD*E_; i += nth) {
        const int c = i / E_;
        const int e = i - c*E_;
        const int n = c >> 6, h = c & 63;
        const int src = (n*E_ + e)*HD + h;       // W_[n][e][h]
        WqT[i] = __float2bfloat16(Wq[src]);
        WkT[i] = __float2bfloat16(Wk[src]);
        WvT[i] = __float2bfloat16(Wv[src]);
        WoT[e*NHD + c] = __float2bfloat16(Wo[i]); // Wo flat[c*E+e] = W_O[n][h][e]
    }
}

// ======================= 256x192 8-phase GEMM core ===========================
// BM=256, BN=192, BK=64, 8 waves (wm 0..1, wn 0..3), wave tile 128x48.
// LDS: 4 DISTINCT __shared__ objects (sA0, sA1, sB0, sB1) so LLVM alias
// analysis can disambiguate in-flight global_load_lds writes from the other
// buffer's ds_reads (single-array version defeats the counted vmcnt).
// Layout (elem units, chunk = 8 bf16 = 16B): A_ELEM(kh,rg) = (kh*16+rg)*512,
// B_ELEM(kh,rg) = (kh*12+rg)*512. Chunk index within a (kh,rg) unit = lane
// (kc=quad, rowlo=l16) -> frag read = 64 consecutive 16B chunks, and
// global_load_lds writes the same linear order (dest = base + lane*16B).
//
// Per 8-phase iteration: 2 K-tiles, 12 MFMA/phase. B-frags loaded in q0, held
// in regs q1..q3. Stage gloads/wave per phase: [2,2,3,0,2,2,3,0], vmcnt(3) at
// phases 4 and 8 only (T4: never drain to 0 in the main loop). Ledger:
//   ph1-2: A(2i+1)->sA1 (sA1 last read prev ph8)     ph3: B(2i+2)->sB0 (read ph1)
//   ph5-6: A(2i+2)->sA0 (last read ph4)              ph7: B(2i+3)->sB1 (read ph5)
// ph4 vmcnt(3): drains prev-ph7 + ph1-2 (all of sA1/sB1 for ph5-8), leaves ph3.
// ph8 vmcnt(3): drains ph3 + ph5-6 (all of sA0/sB0 for next ph1-4), leaves ph7.
// Prologue: A(0)->sA0 (4), B(0)->sB0 (3), B(1)->sB1 (3), vmcnt(3) -> uniform.

#define FENCE() asm volatile("" ::: "memory")
#define VMCNT3() asm volatile("s_waitcnt vmcnt(3)" ::: "memory")

#define A_ELEM(kh, rg) (((kh)*16 + (rg))*512)
#define B_ELEM(kh, rg) (((kh)*12 + (rg))*512)

// stage A-subtile (all 256 rows, khalf kh) of K-tile kt; 2 gloads/wave
#define STG_A(dst, gbase, kt, kh) do {                                            \
    const bf16* _s = (gbase) + (size_t)(l16)*768 + (kt)*64 + (kh)*32 + quad*8;    \
    gload16(_s + (size_t)(w*16)*768,     &(dst)[A_ELEM(kh, w)]);                  \
    gload16(_s + (size_t)((w+8)*16)*768, &(dst)[A_ELEM(kh, w+8)]);                \
} while (0)

// stage B-tile (192 rows, both khalves) of K-tile kt; 3 gloads/wave
#define STG_B(dst, gbase, kt) do {                                                \
    const bf16* _s = (gbase) + (size_t)(l16)*768 + (kt)*64 + quad*8;              \
    const int _k1 = (w < 4) ? 0 : 1;                                              \
    const int _r1 = (w < 4) ? (w + 8) : (w - 4);                                  \
    gload16(_s + (size_t)(w*16)*768,        &(dst)[B_ELEM(0, w)]);                \
    gload16(_s + (size_t)(_r1*16)*768 + _k1*32, &(dst)[B_ELEM(_k1, _r1)]);        \
    gload16(_s + (size_t)((w+4)*16)*768 + 32,   &(dst)[B_ELEM(1, w+4)]);          \
} while (0)

#define PHASE(bufA, bufB, q, LOADB, STAGE, WAIT) do {                             \
    if (LOADB) {                                                                  \
        _Pragma("unroll") for (int n = 0; n < 3; ++n)                             \
        _Pragma("unroll") for (int ks = 0; ks < 2; ++ks)                          \
            bfr[n][ks] = ld8(&(bufB)[((ks)*12 + wn*3 + n)*512 + lane*8]);         \
    }                                                                             \
    bf16x8 afr[2][2];                                                             \
    _Pragma("unroll") for (int m = 0; m < 2; ++m)                                 \
    _Pragma("unroll") for (int ks = 0; ks < 2; ++ks)                              \
        afr[m][ks] = ld8(&(bufA)[((ks)*16 + wm*8 + (q)*2 + m)*512 + lane*8]);     \
    STAGE;                                                                        \
    FENCE(); __builtin_amdgcn_s_barrier(); FENCE();                               \
    asm volatile("s_waitcnt lgkmcnt(0)" ::: "memory");                            \
    __builtin_amdgcn_s_setprio(1);                                                \
    _Pragma("unroll") for (int m = 0; m < 2; ++m)                                 \
    _Pragma("unroll") for (int n = 0; n < 3; ++n)                                 \
    _Pragma("unroll") for (int ks = 0; ks < 2; ++ks)                              \
        acc[(q)*2 + m][n] = mfma16(afr[m][ks], bfr[n][ks], acc[(q)*2 + m][n]);    \
    __builtin_amdgcn_s_setprio(0);                                                \
    WAIT;                                                                         \
    FENCE(); __builtin_amdgcn_s_barrier(); FENCE();                               \
} while (0)

// K = 768 for both GEMMs: 12 K-tiles of 64 -> 6 iterations of 2 K-tiles.
#define GEMM192_BODY(Ab, Bb)                                                      \
    f32x4 acc[8][3];                                                              \
    _Pragma("unroll") for (int mf = 0; mf < 8; ++mf)                              \
    _Pragma("unroll") for (int nf = 0; nf < 3; ++nf)                              \
        acc[mf][nf] = (f32x4){0.f, 0.f, 0.f, 0.f};                                \
    bf16x8 bfr[3][2];                                                             \
    STG_A(sA0, Ab, 0, 0); STG_A(sA0, Ab, 0, 1);                                   \
    STG_B(sB0, Bb, 0);                                                            \
    STG_B(sB1, Bb, 1);                                                            \
    VMCNT3();                                                                     \
    FENCE(); __builtin_amdgcn_s_barrier(); FENCE();                               \
    _Pragma("unroll 1")                                                           \
    for (int i = 0; i < 6; ++i) {                                                 \
        const int kA  = 2*i + 1;                                                  \
        const int kN  = (2*i + 2 < 12) ? 2*i + 2 : 11;                            \
        const int kN3 = (2*i + 3 < 12) ? 2*i + 3 : 11;                            \
        PHASE(sA0, sB0, 0, 1, STG_A(sA1, Ab, kA, 0), (void)0);                    \
        PHASE(sA0, sB0, 1, 0, STG_A(sA1, Ab, kA, 1), (void)0);                    \
        PHASE(sA0, sB0, 2, 0, STG_B(sB0, Bb, kN),    (void)0);                    \
        PHASE(sA0, sB0, 3, 0, (void)0,               VMCNT3());                   \
        PHASE(sA1, sB1, 0, 1, STG_A(sA0, Ab, kN, 0), (void)0);                    \
        PHASE(sA1, sB1, 1, 0, STG_A(sA0, Ab, kN, 1), (void)0);                    \
        PHASE(sA1, sB1, 2, 0, STG_B(sB1, Bb, kN3),   (void)0);                    \
        PHASE(sA1, sB1, 3, 0, (void)0,               VMCNT3());                   \
    }                                                                             \
    asm volatile("s_waitcnt vmcnt(0)" ::: "memory");

// ---------------- QKV projection GEMM (256x192 8-phase) ----------------
// WT = concatenated [WqT; WkT; WvT] = [2304][768]; tn 0..11 spans it.
__global__ __launch_bounds__(512, 2) void qkv_gemm256(
    const bf16* __restrict__ xb, const bf16* __restrict__ WT,
    const float* __restrict__ bq, const float* __restrict__ bk, const float* __restrict__ bv,
    bf16* __restrict__ Qb, bf16* __restrict__ Kb, bf16* __restrict__ VTb)
{
    __shared__ __align__(16) bf16 sA0[16384];
    __shared__ __align__(16) bf16 sA1[16384];
    __shared__ __align__(16) bf16 sB0[12288];
    __shared__ __align__(16) bf16 sB1[12288];

    const int tm = blockIdx.x, tn = blockIdx.y;
    const int lane = threadIdx.x & 63;
    const int w    = threadIdx.x >> 6;      // 0..7
    const int wm = w >> 2, wn = w & 3;
    const int l16 = lane & 15, quad = lane >> 4;
    const bf16* Ab = xb + (size_t)tm*256*E_;
    const bf16* Bb = WT + (size_t)tn*192*E_;

    GEMM192_BODY(Ab, Bb);

    const int mat = tn >> 2;                 // 0=Q 1=K 2=V
    const int cloc0 = (tn & 3)*192 + wn*48;
    const float* bias = (mat==0) ? bq : (mat==1) ? bk : bv;
    const float scale = (mat==0) ? 0.125f * 1.44269504088896340736f : 1.0f;
    bf16* dstQK = (mat==0) ? Qb : Kb;
    #pragma unroll
    for (int nf = 0; nf < 3; ++nf) {
        const int col = cloc0 + nf*16 + l16;       // 0..767 within matrix
        const int hn = col >> 6, h = col & 63;
        const float bb = bias[col];
        #pragma unroll
        for (int mf = 0; mf < 8; ++mf) {
            const int row = tm*256 + wm*128 + mf*16 + quad*4;
            const int bi = row >> 11;              // / S_
            const int s  = row & (S_-1);
            if (mat < 2) {                         // Q,K -> [B][N][S][H]
                bf16* d = dstQK + ((size_t)(bi*NHEADS + hn)*S_ + s)*HD + h;
                #pragma unroll
                for (int r = 0; r < 4; ++r)
                    d[(size_t)r*HD] = __float2bfloat16((acc[mf][nf][r] + bb)*scale);
            } else {                               // V -> transposed [B][N][H][S]
                bf16* d = VTb + ((size_t)(bi*NHEADS + hn)*HD + h)*S_ + s;
                union { bf16x4 v; bf16 e[4]; } u;
                #pragma unroll
                for (int r = 0; r < 4; ++r) u.e[r] = __float2bfloat16(acc[mf][nf][r] + bb);
                *reinterpret_cast<bf16x4*>(d) = u.v;   // s%4==0 -> 8B aligned
            }
        }
    }
}

// ---------------- output projection (256x192 8-phase): out = Z @ Wo + bo -----
__global__ __launch_bounds__(512, 2) void out_gemm256(
    const bf16* __restrict__ Z, const bf16* __restrict__ WoT,
    const float* __restrict__ bo, float* __restrict__ out)
{
    __shared__ __align__(16) bf16 sA0[16384];
    __shared__ __align__(16) bf16 sA1[16384];
    __shared__ __align__(16) bf16 sB0[12288];
    __shared__ __align__(16) bf16 sB1[12288];

    const int tm = blockIdx.x, tn = blockIdx.y;
    const int lane = threadIdx.x & 63;
    const int w    = threadIdx.x >> 6;
    const int wm = w >> 2, wn = w & 3;
    const int l16 = lane & 15, quad = lane >> 4;
    const bf16* Ab = Z   + (size_t)tm*256*NHD;
    const bf16* Bb = WoT + (size_t)tn*192*NHD;

    GEMM192_BODY(Ab, Bb);

    #pragma unroll
    for (int nf = 0; nf < 3; ++nf) {
        const int col = tn*192 + wn*48 + nf*16 + l16;
        const float bb = bo[col];
        #pragma unroll
        for (int mf = 0; mf < 8; ++mf) {
            const int row = tm*256 + wm*128 + mf*16 + quad*4;
            float* d = out + (size_t)row*E_ + col;
            #pragma unroll
            for (int r = 0; r < 4; ++r)
                d[(size_t)r*E_] = acc[mf][nf][r] + bb;
        }
    }
}

// ---------------- flash attention (LDS-staged K/V, double-buffered) -----------
__global__ __launch_bounds__(256, 3) void attn_kernel(
    const bf16* __restrict__ Qb, const bf16* __restrict__ Kb,
    const bf16* __restrict__ VTb, bf16* __restrict__ Z)
{
    __shared__ __align__(16) bf16 sK[2][64*64];
    __shared__ __align__(16) bf16 sV[2][64*64];

    const int id = blockIdx.x;
    const int bx = id / 96;                  // 0..7
    const int g  = id - bx*96;
    const int hn = g % NHEADS, b = g / NHEADS;
    const int tid  = threadIdx.x;
    const int w    = tid >> 6;
    const int lane = tid & 63;
    const int l16 = lane & 15, quad = lane >> 4;
    const size_t bn = (size_t)b*NHEADS + hn;

    const bf16* Qbase = Qb  + bn*S_*HD;
    const bf16* Kbase = Kb  + bn*S_*HD;
    const bf16* Vbase = VTb + bn*HD*S_;

    const int mA = tid, mB = tid + 256;
    const int rA = mA >> 3, cgA = mA & 7;
    const int rB = mB >> 3, cgB = mB & 7;
    const int slA = (rA*8 + ((cgA + rA + (rA>>3)) & 7)) * 8;
    const int slB = (rB*8 + ((cgB + rB + (rB>>3)) & 7)) * 8;
    const size_t vofA = (size_t)rA*S_ + cgA*8;
    const size_t vofB = (size_t)rB*S_ + cgB*8;

    const int kperm = (l16 >> 2)*8 + (l16 & 3);
    int kidx[2][2][2];
    #pragma unroll
    for (int c=0;c<2;c++)
        #pragma unroll
        for (int bg=0;bg<2;bg++)
            #pragma unroll
            for (int hf=0;hf<2;hf++) {
                const int r = 32*c + 4*bg + kperm;
                const int q = hf*4 + quad;
                kidx[c][bg][hf] = (r*8 + ((q + r + (r>>3)) & 7)) * 8;
            }
    int vidx[4][2];
    #pragma unroll
    for (int ht=0;ht<4;ht++)
        #pragma unroll
        for (int c=0;c<2;c++) {
            const int rho = ht*16 + l16;
            const int q = c*4 + quad;
            vidx[ht][c] = (rho*8 + ((q + rho + (rho>>3)) & 7)) * 8;
        }

    #pragma unroll
    for (int half = 0; half < 2; ++half) {
        const int qblk = half ? (S_/128 - 1 - bx) : bx;
        const int ktb  = 2*qblk + 1;
        const int ktw  = 2*qblk + (w >> 1);
        const int qbase = qblk*128 + w*32;

        bf16x8 bqf[2][2];
        #pragma unroll
        for (int qi=0;qi<2;qi++)
            #pragma unroll
            for (int hf=0;hf<2;hf++)
                bqf[qi][hf] = ld8(Qbase + (size_t)(qbase + qi*16 + l16)*HD + hf*32 + quad*8);

        f32x4 acc[2][4];
        #pragma unroll
        for (int qi=0;qi<2;qi++)
            #pragma unroll
            for (int ht=0;ht<4;ht++) acc[qi][ht] = (f32x4){0.f,0.f,0.f,0.f};
        float lsum[2] = {0.f, 0.f};

        bf16x8 k0 = ld8(Kbase + (size_t)mA*8);
        bf16x8 k1 = ld8(Kbase + (size_t)mB*8);
        bf16x8 v0 = ld8(Vbase + vofA);
        bf16x8 v1 = ld8(Vbase + vofB);
        *reinterpret_cast<bf16x8*>(&sK[0][slA]) = k0;
        *reinterpret_cast<bf16x8*>(&sK[0][slB]) = k1;
        *reinterpret_cast<bf16x8*>(&sV[0][slA]) = v0;
        *reinterpret_cast<bf16x8*>(&sV[0][slB]) = v1;
        __syncthreads();

        for (int kt = 0; kt <= ktb; ++kt) {
            if (kt < ktb) {
                const size_t kt1 = (size_t)(kt+1)*64;
                k0 = ld8(Kbase + kt1*HD + (size_t)mA*8);
                k1 = ld8(Kbase + kt1*HD + (size_t)mB*8);
                v0 = ld8(Vbase + vofA + kt1);
                v1 = ld8(Vbase + vofB + kt1);
            }
            if (kt <= ktw) {
                const bf16* kb = sK[kt & 1];
                const bf16* vb = sV[kt & 1];
                #pragma unroll
                for (int c=0;c<2;c++) {
                    const bf16x8 akA0 = ld8(kb + kidx[c][0][0]);
                    const bf16x8 akA1 = ld8(kb + kidx[c][0][1]);
                    const bf16x8 akB0 = ld8(kb + kidx[c][1][0]);
                    const bf16x8 akB1 = ld8(kb + kidx[c][1][1]);
                    bf16x8 av[4];
                    #pragma unroll
                    for (int ht=0;ht<4;ht++) av[ht] = ld8(vb + vidx[ht][c]);

                    #pragma unroll
                    for (int qi=0;qi<2;qi++) {
                        f32x4 s0 = (f32x4){0.f,0.f,0.f,0.f};
                        s0 = mfma16(akA0, bqf[qi][0], s0);
                        s0 = mfma16(akA1, bqf[qi][1], s0);
                        f32x4 s1 = (f32x4){0.f,0.f,0.f,0.f};
                        s1 = mfma16(akB0, bqf[qi][0], s1);
                        s1 = mfma16(akB1, bqf[qi][1], s1);
                        if (kt == ktw) {
                            const int q  = qbase + qi*16 + l16;
                            const int kb0 = kt*64 + c*32 + quad*8;
                            #pragma unroll
                            for (int r=0;r<4;r++) {
                                s0[r] = (kb0 + r     > q) ? -1e30f : s0[r];
                                s1[r] = (kb0 + 4 + r > q) ? -1e30f : s1[r];
                            }
                        }
                        float ls = 0.f;
                        #pragma unroll
                        for (int r=0;r<4;r++) {
                            s0[r] = __builtin_amdgcn_exp2f(s0[r]);
                            s1[r] = __builtin_amdgcn_exp2f(s1[r]);
                            ls += s0[r] + s1[r];
                        }
                        lsum[qi] += ls;
                        const bf16x8 pf = pack8(s0, s1);
                        #pragma unroll
                        for (int ht=0;ht<4;ht++)
                            acc[qi][ht] = mfma16(av[ht], pf, acc[qi][ht]);
                    }
                }
            }
            if (kt < ktb) {
                const int nb = (kt+1) & 1;
                *reinterpret_cast<bf16x8*>(&sK[nb][slA]) = k0;
                *reinterpret_cast<bf16x8*>(&sK[nb][slB]) = k1;
                *reinterpret_cast<bf16x8*>(&sV[nb][slA]) = v0;
                *reinterpret_cast<bf16x8*>(&sV[nb][slB]) = v1;
            }
            __syncthreads();
        }

        #pragma unroll
        for (int qi=0;qi<2;qi++) {
            float rs = lsum[qi];
            rs += __shfl_xor(rs, 16, 64);
            rs += __shfl_xor(rs, 32, 64);
            const float inv_l = 1.0f / rs;
            const int q = qbase + qi*16 + l16;
            bf16* zp = Z + ((size_t)b*S_ + q)*NHD + (size_t)hn*HD + quad*4;
            #pragma unroll
            for (int ht=0;ht<4;ht++) {
                union { bf16x4 v; bf16 e[4]; } u;
                #pragma unroll
                for (int r=0;r<4;r++) u.e[r] = __float2bfloat16(acc[qi][ht][r] * inv_l);
                *reinterpret_cast<bf16x4*>(zp + ht*16) = u.v;
            }
        }
    }
}

extern "C" void kernel_launch(void* const* d_in, const int* in_sizes, int n_in,
                              void* d_out, int out_size, void* d_ws, size_t ws_size,
                              hipStream_t stream)
{
    const float* x  = (const float*)d_in[0];
    const float* Wq = (const float*)d_in[1];
    const float* Wk = (const float*)d_in[2];
    const float* Wv = (const float*)d_in[3];
    const float* Wo = (const float*)d_in[4];
    const float* bq = (const float*)d_in[5];
    const float* bk = (const float*)d_in[6];
    const float* bv = (const float*)d_in[7];
    const float* bo = (const float*)d_in[8];
    float* out = (float*)d_out;

    char* ws = (char*)d_ws;
    size_t off = 0;
    auto alloc = [&](size_t bytes){ char* p = ws + off; off += (bytes + 255) & ~(size_t)255; return p; };
    bf16* xb  = (bf16*)alloc((size_t)BS*E_*2);
    bf16* WT  = (bf16*)alloc((size_t)3*NHD*E_*2);  // [WqT; WkT; WvT] = [2304][768]
    bf16* WoT = (bf16*)alloc((size_t)E_*NHD*2);
    bf16* Qb  = (bf16*)alloc((size_t)BS*NHD*2);   // [B][N][S][H], pre-scaled log2e/8
    bf16* Kb  = (bf16*)alloc((size_t)BS*NHD*2);   // [B][N][S][H]
    bf16* VTb = (bf16*)alloc((size_t)BS*NHD*2);   // [B][N][H][S]
    bf16* Zb  = (bf16*)alloc((size_t)BS*NHD*2);   // [BS][NHD]

    bf16* WqT = WT;
    bf16* WkT = WT + (size_t)NHD*E_;
    bf16* WvT = WT + (size_t)2*NHD*E_;

    prep_kernel<<<4096, 256, 0, stream>>>(x, Wq, Wk, Wv, Wo, xb, WqT, WkT, WvT, WoT);
    qkv_gemm256<<<dim3(BS/256, 12), 512, 0, stream>>>(xb, WT, bq, bk, bv, Qb, Kb, VTb);
    attn_kernel<<<768, 256, 0, stream>>>(Qb, Kb, VTb, Zb);
    out_gemm256<<<dim3(BS/256, E_/192), 512, 0, stream>>>(Zb, WoT, bo, out);
}

// Round 3
// 232.235 us; speedup vs baseline: 1.1143x; 1.0258x over previous
//
#include <hip/hip_runtime.h>
#include <hip/hip_bf16.h>
#include <stdint.h>

// Causal MHA, B=8 S=2048 E=768 N=12 H=64. fp32 in/out, bf16 MFMA compute.
// prep -> QKV gemm (256x192 8-phase, triple-buffered A, vmcnt(7) deep pipeline)
// -> flash attention (LDS-staged K/V, register-P, paired strips)
// -> out gemm (same structure).

#define B_ 8
#define S_ 2048
#define E_ 768
#define NHEADS 12
#define HD 64
#define BS (B_*S_)        // 16384
#define NHD (NHEADS*HD)   // 768

typedef short bf16x8 __attribute__((ext_vector_type(8)));   // 8 bf16 = 4 VGPR
typedef short bf16x4 __attribute__((ext_vector_type(4)));
typedef float f32x4  __attribute__((ext_vector_type(4)));   // MFMA C/D frag
typedef __hip_bfloat16 bf16;

typedef const __attribute__((address_space(1))) char* as1_t;
typedef __attribute__((address_space(3))) char* as3_t;

__device__ __forceinline__ f32x4 mfma16(bf16x8 a, bf16x8 b, f32x4 c) {
    return __builtin_amdgcn_mfma_f32_16x16x32_bf16(a, b, c, 0, 0, 0);
}
__device__ __forceinline__ bf16x8 ld8(const bf16* p) {
    return *reinterpret_cast<const bf16x8*>(p);
}
// async global->LDS, 16B/lane; lds dest = wave-uniform base + lane*16
__device__ __forceinline__ void gload16(const bf16* g, bf16* l) {
    __builtin_amdgcn_global_load_lds((as1_t)g, (as3_t)l, 16, 0, 0);
}
__device__ __forceinline__ bf16x8 pack8(f32x4 a, f32x4 b) {
    union { bf16x8 v; __hip_bfloat162 h[4]; } u;
    u.h[0] = __float22bfloat162_rn(make_float2(a[0], a[1]));
    u.h[1] = __float22bfloat162_rn(make_float2(a[2], a[3]));
    u.h[2] = __float22bfloat162_rn(make_float2(b[0], b[1]));
    u.h[3] = __float22bfloat162_rn(make_float2(b[2], b[3]));
    return u.v;
}

// ---------------- prep: fp32 -> bf16 casts + weight transposes ----------------
__global__ __launch_bounds__(256) void prep_kernel(
    const float* __restrict__ x,  const float* __restrict__ Wq,
    const float* __restrict__ Wk, const float* __restrict__ Wv,
    const float* __restrict__ Wo,
    bf16* __restrict__ xb,  bf16* __restrict__ WqT, bf16* __restrict__ WkT,
    bf16* __restrict__ WvT, bf16* __restrict__ WoT)
{
    const int tid = blockIdx.x * 256 + threadIdx.x;
    const int nth = gridDim.x * 256;
    for (int i = tid; i < BS*E_; i += nth)
        xb[i] = __float2bfloat16(x[i]);
    for (int i = tid; i < NHD*E_; i += nth) {
        const int c = i / E_;
        const int e = i - c*E_;
        const int n = c >> 6, h = c & 63;
        const int src = (n*E_ + e)*HD + h;       // W_[n][e][h]
        WqT[i] = __float2bfloat16(Wq[src]);
        WkT[i] = __float2bfloat16(Wk[src]);
        WvT[i] = __float2bfloat16(Wv[src]);
        WoT[e*NHD + c] = __float2bfloat16(Wo[i]); // Wo flat[c*E+e] = W_O[n][h][e]
    }
}

// ======================= 256x192 8-phase GEMM core ===========================
// BM=256, BN=192, BK=64, 8 waves (wm 0..1, wn 0..3), wave tile 128x48.
// A TRIPLE-buffered (sA0/sA1/sA2, 32KB each), B double (sB0/sB1, 24KB) =
// 144 KB LDS. Deep pipeline: iteration i reads A(2i) from r0 (ph1-4) and
// A(2i+1) from r1 (ph5-8); stages A(2i+2)->w at ph1-2, B(2i+2)->sB0 at ph3,
// A(2i+3)->r0 at ph5-6 (r0 free after ph4), B(2i+3)->sB1 at ph7. Buffer roles
// rotate (r0,r1,w) -> (w,r0,r1), period 3 -> 3 statically-named ITERs.
// Per-phase gload counts [2,2,3,0,2,2,3,0]; vmcnt(7) at ph4 waits exactly for
// prev-iter ph5-7 (A(2i+1)+B(2i+1), issued 5-7 phases ago); vmcnt(7) at ph8
// waits for this-iter ph1-3 (A(2i+2)+B(2i+2)). Loads in flight are never
// younger than 5 phases at a wait -> ~1000+ cyc latency cover (T4 deep).
// Prologue issues A(0),B(0),A(1),B(1) in that order; vmcnt(7) drains A(0)+B(0)
// (oldest 7), leaving A(1)+B(1) in flight -> wait counts uniform from iter 0.
// Tail: stage kt clamped to 11 (restage of live data into dead buffers; safe).

#define FENCE() asm volatile("" ::: "memory")
#define VMCNT7() asm volatile("s_waitcnt vmcnt(7)" ::: "memory")
#define MIN11(x) ((x) < 11 ? (x) : 11)

#define A_ELEM(kh, rg) (((kh)*16 + (rg))*512)
#define B_ELEM(kh, rg) (((kh)*12 + (rg))*512)

// stage A-subtile (all 256 rows, khalf kh) of K-tile kt; 2 gloads/wave
#define STG_A(dst, gbase, kt, kh) do {                                            \
    const bf16* _s = (gbase) + (size_t)(l16)*768 + (kt)*64 + (kh)*32 + quad*8;    \
    gload16(_s + (size_t)(w*16)*768,     &(dst)[A_ELEM(kh, w)]);                  \
    gload16(_s + (size_t)((w+8)*16)*768, &(dst)[A_ELEM(kh, w+8)]);                \
} while (0)

// stage B-tile (192 rows, both khalves) of K-tile kt; 3 gloads/wave
#define STG_B(dst, gbase, kt) do {                                                \
    const bf16* _s = (gbase) + (size_t)(l16)*768 + (kt)*64 + quad*8;              \
    const int _k1 = (w < 4) ? 0 : 1;                                              \
    const int _r1 = (w < 4) ? (w + 8) : (w - 4);                                  \
    gload16(_s + (size_t)(w*16)*768,        &(dst)[B_ELEM(0, w)]);                \
    gload16(_s + (size_t)(_r1*16)*768 + _k1*32, &(dst)[B_ELEM(_k1, _r1)]);        \
    gload16(_s + (size_t)((w+4)*16)*768 + 32,   &(dst)[B_ELEM(1, w+4)]);          \
} while (0)

#define PHASE(bufA, bufB, q, LOADB, STAGE, WAIT) do {                             \
    if (LOADB) {                                                                  \
        _Pragma("unroll") for (int n = 0; n < 3; ++n)                             \
        _Pragma("unroll") for (int ks = 0; ks < 2; ++ks)                          \
            bfr[n][ks] = ld8(&(bufB)[((ks)*12 + wn*3 + n)*512 + lane*8]);         \
    }                                                                             \
    bf16x8 afr[2][2];                                                             \
    _Pragma("unroll") for (int m = 0; m < 2; ++m)                                 \
    _Pragma("unroll") for (int ks = 0; ks < 2; ++ks)                              \
        afr[m][ks] = ld8(&(bufA)[((ks)*16 + wm*8 + (q)*2 + m)*512 + lane*8]);     \
    STAGE;                                                                        \
    FENCE(); __builtin_amdgcn_s_barrier(); FENCE();                               \
    asm volatile("s_waitcnt lgkmcnt(0)" ::: "memory");                            \
    __builtin_amdgcn_s_setprio(1);                                                \
    _Pragma("unroll") for (int m = 0; m < 2; ++m)                                 \
    _Pragma("unroll") for (int n = 0; n < 3; ++n)                                 \
    _Pragma("unroll") for (int ks = 0; ks < 2; ++ks)                              \
        acc[(q)*2 + m][n] = mfma16(afr[m][ks], bfr[n][ks], acc[(q)*2 + m][n]);    \
    __builtin_amdgcn_s_setprio(0);                                                \
    WAIT;                                                                         \
    FENCE(); __builtin_amdgcn_s_barrier(); FENCE();                               \
} while (0)

// One deep-pipeline iteration: reads A(k0) from r0, A(k0+1) from r1;
// stages A(k0+2)->w, B(k0+2)->sB0, A(k0+3)->r0, B(k0+3)->sB1 (clamped).
#define ITER8(r0, r1, w2, k0, Ab, Bb)                                             \
    PHASE(r0, sB0, 0, 1, STG_A(w2, Ab, MIN11((k0)+2), 0), (void)0);               \
    PHASE(r0, sB0, 1, 0, STG_A(w2, Ab, MIN11((k0)+2), 1), (void)0);               \
    PHASE(r0, sB0, 2, 0, STG_B(sB0, Bb, MIN11((k0)+2)),   (void)0);               \
    PHASE(r0, sB0, 3, 0, (void)0,                         VMCNT7());              \
    PHASE(r1, sB1, 0, 1, STG_A(r0, Ab, MIN11((k0)+3), 0), (void)0);               \
    PHASE(r1, sB1, 1, 0, STG_A(r0, Ab, MIN11((k0)+3), 1), (void)0);               \
    PHASE(r1, sB1, 2, 0, STG_B(sB1, Bb, MIN11((k0)+3)),   (void)0);               \
    PHASE(r1, sB1, 3, 0, (void)0,                         VMCNT7());

// K = 768 for both GEMMs: 12 K-tiles of 64 -> 6 iterations (2 outer x 3 named).
#define GEMM192_BODY(Ab, Bb)                                                      \
    f32x4 acc[8][3];                                                              \
    _Pragma("unroll") for (int mf = 0; mf < 8; ++mf)                              \
    _Pragma("unroll") for (int nf = 0; nf < 3; ++nf)                              \
        acc[mf][nf] = (f32x4){0.f, 0.f, 0.f, 0.f};                                \
    bf16x8 bfr[3][2];                                                             \
    STG_A(sA0, Ab, 0, 0); STG_A(sA0, Ab, 0, 1);                                   \
    STG_B(sB0, Bb, 0);                                                            \
    STG_A(sA1, Ab, 1, 0); STG_A(sA1, Ab, 1, 1);                                   \
    STG_B(sB1, Bb, 1);                                                            \
    VMCNT7();                                                                     \
    FENCE(); __builtin_amdgcn_s_barrier(); FENCE();                               \
    _Pragma("unroll 1")                                                           \
    for (int ii = 0; ii < 2; ++ii) {                                              \
        const int k0 = 6*ii;                                                      \
        ITER8(sA0, sA1, sA2, k0+0, Ab, Bb)                                        \
        ITER8(sA2, sA0, sA1, k0+2, Ab, Bb)                                        \
        ITER8(sA1, sA2, sA0, k0+4, Ab, Bb)                                        \
    }                                                                             \
    asm volatile("s_waitcnt vmcnt(0)" ::: "memory");

// ---------------- QKV projection GEMM (256x192 8-phase) ----------------
// WT = concatenated [WqT; WkT; WvT] = [2304][768]; tn 0..11 spans it.
__global__ __launch_bounds__(512, 2) void qkv_gemm256(
    const bf16* __restrict__ xb, const bf16* __restrict__ WT,
    const float* __restrict__ bq, const float* __restrict__ bk, const float* __restrict__ bv,
    bf16* __restrict__ Qb, bf16* __restrict__ Kb, bf16* __restrict__ VTb)
{
    __shared__ __align__(16) bf16 sA0[16384];
    __shared__ __align__(16) bf16 sA1[16384];
    __shared__ __align__(16) bf16 sA2[16384];
    __shared__ __align__(16) bf16 sB0[12288];
    __shared__ __align__(16) bf16 sB1[12288];

    const int tm = blockIdx.x, tn = blockIdx.y;
    const int lane = threadIdx.x & 63;
    const int w    = threadIdx.x >> 6;      // 0..7
    const int wm = w >> 2, wn = w & 3;
    const int l16 = lane & 15, quad = lane >> 4;
    const bf16* Ab = xb + (size_t)tm*256*E_;
    const bf16* Bb = WT + (size_t)tn*192*E_;

    GEMM192_BODY(Ab, Bb);

    const int mat = tn >> 2;                 // 0=Q 1=K 2=V
    const int cloc0 = (tn & 3)*192 + wn*48;
    const float* bias = (mat==0) ? bq : (mat==1) ? bk : bv;
    const float scale = (mat==0) ? 0.125f * 1.44269504088896340736f : 1.0f;
    bf16* dstQK = (mat==0) ? Qb : Kb;
    #pragma unroll
    for (int nf = 0; nf < 3; ++nf) {
        const int col = cloc0 + nf*16 + l16;       // 0..767 within matrix
        const int hn = col >> 6, h = col & 63;
        const float bb = bias[col];
        #pragma unroll
        for (int mf = 0; mf < 8; ++mf) {
            const int row = tm*256 + wm*128 + mf*16 + quad*4;
            const int bi = row >> 11;              // / S_
            const int s  = row & (S_-1);
            if (mat < 2) {                         // Q,K -> [B][N][S][H]
                bf16* d = dstQK + ((size_t)(bi*NHEADS + hn)*S_ + s)*HD + h;
                #pragma unroll
                for (int r = 0; r < 4; ++r)
                    d[(size_t)r*HD] = __float2bfloat16((acc[mf][nf][r] + bb)*scale);
            } else {                               // V -> transposed [B][N][H][S]
                bf16* d = VTb + ((size_t)(bi*NHEADS + hn)*HD + h)*S_ + s;
                union { bf16x4 v; bf16 e[4]; } u;
                #pragma unroll
                for (int r = 0; r < 4; ++r) u.e[r] = __float2bfloat16(acc[mf][nf][r] + bb);
                *reinterpret_cast<bf16x4*>(d) = u.v;   // s%4==0 -> 8B aligned
            }
        }
    }
}

// ---------------- output projection (256x192 8-phase): out = Z @ Wo + bo -----
__global__ __launch_bounds__(512, 2) void out_gemm256(
    const bf16* __restrict__ Z, const bf16* __restrict__ WoT,
    const float* __restrict__ bo, float* __restrict__ out)
{
    __shared__ __align__(16) bf16 sA0[16384];
    __shared__ __align__(16) bf16 sA1[16384];
    __shared__ __align__(16) bf16 sA2[16384];
    __shared__ __align__(16) bf16 sB0[12288];
    __shared__ __align__(16) bf16 sB1[12288];

    const int tm = blockIdx.x, tn = blockIdx.y;
    const int lane = threadIdx.x & 63;
    const int w    = threadIdx.x >> 6;
    const int wm = w >> 2, wn = w & 3;
    const int l16 = lane & 15, quad = lane >> 4;
    const bf16* Ab = Z   + (size_t)tm*256*NHD;
    const bf16* Bb = WoT + (size_t)tn*192*NHD;

    GEMM192_BODY(Ab, Bb);

    #pragma unroll
    for (int nf = 0; nf < 3; ++nf) {
        const int col = tn*192 + wn*48 + nf*16 + l16;
        const float bb = bo[col];
        #pragma unroll
        for (int mf = 0; mf < 8; ++mf) {
            const int row = tm*256 + wm*128 + mf*16 + quad*4;
            float* d = out + (size_t)row*E_ + col;
            #pragma unroll
            for (int r = 0; r < 4; ++r)
                d[(size_t)r*E_] = acc[mf][nf][r] + bb;
        }
    }
}

// ---------------- flash attention (LDS-staged K/V, double-buffered) -----------
__global__ __launch_bounds__(256, 3) void attn_kernel(
    const bf16* __restrict__ Qb, const bf16* __restrict__ Kb,
    const bf16* __restrict__ VTb, bf16* __restrict__ Z)
{
    __shared__ __align__(16) bf16 sK[2][64*64];
    __shared__ __align__(16) bf16 sV[2][64*64];

    const int id = blockIdx.x;
    const int bx = id / 96;                  // 0..7
    const int g  = id - bx*96;
    const int hn = g % NHEADS, b = g / NHEADS;
    const int tid  = threadIdx.x;
    const int w    = tid >> 6;
    const int lane = tid & 63;
    const int l16 = lane & 15, quad = lane >> 4;
    const size_t bn = (size_t)b*NHEADS + hn;

    const bf16* Qbase = Qb  + bn*S_*HD;
    const bf16* Kbase = Kb  + bn*S_*HD;
    const bf16* Vbase = VTb + bn*HD*S_;

    const int mA = tid, mB = tid + 256;
    const int rA = mA >> 3, cgA = mA & 7;
    const int rB = mB >> 3, cgB = mB & 7;
    const int slA = (rA*8 + ((cgA + rA + (rA>>3)) & 7)) * 8;
    const int slB = (rB*8 + ((cgB + rB + (rB>>3)) & 7)) * 8;
    const size_t vofA = (size_t)rA*S_ + cgA*8;
    const size_t vofB = (size_t)rB*S_ + cgB*8;

    const int kperm = (l16 >> 2)*8 + (l16 & 3);
    int kidx[2][2][2];
    #pragma unroll
    for (int c=0;c<2;c++)
        #pragma unroll
        for (int bg=0;bg<2;bg++)
            #pragma unroll
            for (int hf=0;hf<2;hf++) {
                const int r = 32*c + 4*bg + kperm;
                const int q = hf*4 + quad;
                kidx[c][bg][hf] = (r*8 + ((q + r + (r>>3)) & 7)) * 8;
            }
    int vidx[4][2];
    #pragma unroll
    for (int ht=0;ht<4;ht++)
        #pragma unroll
        for (int c=0;c<2;c++) {
            const int rho = ht*16 + l16;
            const int q = c*4 + quad;
            vidx[ht][c] = (rho*8 + ((q + rho + (rho>>3)) & 7)) * 8;
        }

    #pragma unroll
    for (int half = 0; half < 2; ++half) {
        const int qblk = half ? (S_/128 - 1 - bx) : bx;
        const int ktb  = 2*qblk + 1;
        const int ktw  = 2*qblk + (w >> 1);
        const int qbase = qblk*128 + w*32;

        bf16x8 bqf[2][2];
        #pragma unroll
        for (int qi=0;qi<2;qi++)
            #pragma unroll
            for (int hf=0;hf<2;hf++)
                bqf[qi][hf] = ld8(Qbase + (size_t)(qbase + qi*16 + l16)*HD + hf*32 + quad*8);

        f32x4 acc[2][4];
        #pragma unroll
        for (int qi=0;qi<2;qi++)
            #pragma unroll
            for (int ht=0;ht<4;ht++) acc[qi][ht] = (f32x4){0.f,0.f,0.f,0.f};
        float lsum[2] = {0.f, 0.f};

        bf16x8 k0 = ld8(Kbase + (size_t)mA*8);
        bf16x8 k1 = ld8(Kbase + (size_t)mB*8);
        bf16x8 v0 = ld8(Vbase + vofA);
        bf16x8 v1 = ld8(Vbase + vofB);
        *reinterpret_cast<bf16x8*>(&sK[0][slA]) = k0;
        *reinterpret_cast<bf16x8*>(&sK[0][slB]) = k1;
        *reinterpret_cast<bf16x8*>(&sV[0][slA]) = v0;
        *reinterpret_cast<bf16x8*>(&sV[0][slB]) = v1;
        __syncthreads();

        for (int kt = 0; kt <= ktb; ++kt) {
            if (kt < ktb) {
                const size_t kt1 = (size_t)(kt+1)*64;
                k0 = ld8(Kbase + kt1*HD + (size_t)mA*8);
                k1 = ld8(Kbase + kt1*HD + (size_t)mB*8);
                v0 = ld8(Vbase + vofA + kt1);
                v1 = ld8(Vbase + vofB + kt1);
            }
            if (kt <= ktw) {
                const bf16* kb = sK[kt & 1];
                const bf16* vb = sV[kt & 1];
                #pragma unroll
                for (int c=0;c<2;c++) {
                    const bf16x8 akA0 = ld8(kb + kidx[c][0][0]);
                    const bf16x8 akA1 = ld8(kb + kidx[c][0][1]);
                    const bf16x8 akB0 = ld8(kb + kidx[c][1][0]);
                    const bf16x8 akB1 = ld8(kb + kidx[c][1][1]);
                    bf16x8 av[4];
                    #pragma unroll
                    for (int ht=0;ht<4;ht++) av[ht] = ld8(vb + vidx[ht][c]);

                    #pragma unroll
                    for (int qi=0;qi<2;qi++) {
                        f32x4 s0 = (f32x4){0.f,0.f,0.f,0.f};
                        s0 = mfma16(akA0, bqf[qi][0], s0);
                        s0 = mfma16(akA1, bqf[qi][1], s0);
                        f32x4 s1 = (f32x4){0.f,0.f,0.f,0.f};
                        s1 = mfma16(akB0, bqf[qi][0], s1);
                        s1 = mfma16(akB1, bqf[qi][1], s1);
                        if (kt == ktw) {
                            const int q  = qbase + qi*16 + l16;
                            const int kb0 = kt*64 + c*32 + quad*8;
                            #pragma unroll
                            for (int r=0;r<4;r++) {
                                s0[r] = (kb0 + r     > q) ? -1e30f : s0[r];
                                s1[r] = (kb0 + 4 + r > q) ? -1e30f : s1[r];
                            }
                        }
                        float ls = 0.f;
                        #pragma unroll
                        for (int r=0;r<4;r++) {
                            s0[r] = __builtin_amdgcn_exp2f(s0[r]);
                            s1[r] = __builtin_amdgcn_exp2f(s1[r]);
                            ls += s0[r] + s1[r];
                        }
                        lsum[qi] += ls;
                        const bf16x8 pf = pack8(s0, s1);
                        #pragma unroll
                        for (int ht=0;ht<4;ht++)
                            acc[qi][ht] = mfma16(av[ht], pf, acc[qi][ht]);
                    }
                }
            }
            if (kt < ktb) {
                const int nb = (kt+1) & 1;
                *reinterpret_cast<bf16x8*>(&sK[nb][slA]) = k0;
                *reinterpret_cast<bf16x8*>(&sK[nb][slB]) = k1;
                *reinterpret_cast<bf16x8*>(&sV[nb][slA]) = v0;
                *reinterpret_cast<bf16x8*>(&sV[nb][slB]) = v1;
            }
            __syncthreads();
        }

        #pragma unroll
        for (int qi=0;qi<2;qi++) {
            float rs = lsum[qi];
            rs += __shfl_xor(rs, 16, 64);
            rs += __shfl_xor(rs, 32, 64);
            const float inv_l = 1.0f / rs;
            const int q = qbase + qi*16 + l16;
            bf16* zp = Z + ((size_t)b*S_ + q)*NHD + (size_t)hn*HD + quad*4;
            #pragma unroll
            for (int ht=0;ht<4;ht++) {
                union { bf16x4 v; bf16 e[4]; } u;
                #pragma unroll
                for (int r=0;r<4;r++) u.e[r] = __float2bfloat16(acc[qi][ht][r] * inv_l);
                *reinterpret_cast<bf16x4*>(zp + ht*16) = u.v;
            }
        }
    }
}

extern "C" void kernel_launch(void* const* d_in, const int* in_sizes, int n_in,
                              void* d_out, int out_size, void* d_ws, size_t ws_size,
                              hipStream_t stream)
{
    const float* x  = (const float*)d_in[0];
    const float* Wq = (const float*)d_in[1];
    const float* Wk = (const float*)d_in[2];
    const float* Wv = (const float*)d_in[3];
    const float* Wo = (const float*)d_in[4];
    const float* bq = (const float*)d_in[5];
    const float* bk = (const float*)d_in[6];
    const float* bv = (const float*)d_in[7];
    const float* bo = (const float*)d_in[8];
    float* out = (float*)d_out;

    char* ws = (char*)d_ws;
    size_t off = 0;
    auto alloc = [&](size_t bytes){ char* p = ws + off; off += (bytes + 255) & ~(size_t)255; return p; };
    bf16* xb  = (bf16*)alloc((size_t)BS*E_*2);
    bf16* WT  = (bf16*)alloc((size_t)3*NHD*E_*2);  // [WqT; WkT; WvT] = [2304][768]
    bf16* WoT = (bf16*)alloc((size_t)E_*NHD*2);
    bf16* Qb  = (bf16*)alloc((size_t)BS*NHD*2);   // [B][N][S][H], pre-scaled log2e/8
    bf16* Kb  = (bf16*)alloc((size_t)BS*NHD*2);   // [B][N][S][H]
    bf16* VTb = (bf16*)alloc((size_t)BS*NHD*2);   // [B][N][H][S]
    bf16* Zb  = (bf16*)alloc((size_t)BS*NHD*2);   // [BS][NHD]

    bf16* WqT = WT;
    bf16* WkT = WT + (size_t)NHD*E_;
    bf16* WvT = WT + (size_t)2*NHD*E_;

    prep_kernel<<<4096, 256, 0, stream>>>(x, Wq, Wk, Wv, Wo, xb, WqT, WkT, WvT, WoT);
    qkv_gemm256<<<dim3(BS/256, 12), 512, 0, stream>>>(xb, WT, bq, bk, bv, Qb, Kb, VTb);
    attn_kernel<<<768, 256, 0, stream>>>(Qb, Kb, VTb, Zb);
    out_gemm256<<<dim3(BS/256, E_/192), 512, 0, stream>>>(Zb, WoT, bo, out);
}